// Round 1
// baseline (604.532 us; speedup 1.0000x reference)
//
#include <hip/hip_runtime.h>

typedef __attribute__((ext_vector_type(8))) short short8;
typedef __attribute__((ext_vector_type(4))) float f32x4;
typedef unsigned short ushort_t;
typedef unsigned int uint_t;

#define MFMA16(a, b, c) __builtin_amdgcn_mfma_f32_16x16x32_bf16((a), (b), (c), 0, 0, 0)

constexpr int V = 10000;
constexpr int E = 640000;

__device__ __forceinline__ ushort_t f2b(float f) {
    // fp32 -> bf16 round-to-nearest-even (finite inputs)
    uint_t u = __float_as_uint(f);
    u += 0x7FFFu + ((u >> 16) & 1u);
    return (ushort_t)(u >> 16);
}

__device__ __forceinline__ float silu(float x) {
    return x / (1.0f + __expf(-x));
}

__device__ __forceinline__ uint_t cvt_pk_bf16(float lo, float hi) {
    // D.lo = bf16(lo), D.hi = bf16(hi), RNE
    uint_t r;
    asm("v_cvt_pk_bf16_f32 %0, %1, %2" : "=v"(r) : "v"(lo), "v"(hi));
    return r;
}

// Workgroup barrier that orders LDS only: does NOT drain vmcnt, so global
// stores / atomics issued before it stay in flight across tiles.
__device__ __forceinline__ void wg_barrier_lds() {
    asm volatile("s_waitcnt lgkmcnt(0)" ::: "memory");
    __builtin_amdgcn_s_barrier();
    asm volatile("" ::: "memory");
}

// ---------------------------------------------------------------------------
// prep: one kernel does h->bf16, agg zero-fill, and the 4 weight matrices
// bf16-convert + TRANSPOSE (so MFMA B-fragments load as contiguous b128).
// wT layout: [col][k], i.e. wT[c*K + k] = w[k*NCOL + c].
// ---------------------------------------------------------------------------
__global__ void prep(const float* __restrict__ h,
                     const float* __restrict__ ew1, const float* __restrict__ ew2,
                     const float* __restrict__ nw1, const float* __restrict__ nw2,
                     ushort_t* __restrict__ hb,
                     ushort_t* __restrict__ w1T, ushort_t* __restrict__ w2T,
                     ushort_t* __restrict__ nw1T, ushort_t* __restrict__ nw2T,
                     float* __restrict__ agg) {
    int i = blockIdx.x * blockDim.x + threadIdx.x;
    if (i < V * 128) { hb[i] = f2b(h[i]); return; }
    i -= V * 128;
    if (i < V * 128) { agg[i] = 0.0f; return; }
    i -= V * 128;
    if (i < 256 * 128) { int k = i >> 7, c = i & 127; w1T[c * 256 + k] = f2b(ew1[i]); return; }
    i -= 256 * 128;
    if (i < 128 * 128) { int k = i >> 7, c = i & 127; w2T[c * 128 + k] = f2b(ew2[i]); return; }
    i -= 128 * 128;
    if (i < 256 * 128) { int k = i >> 7, c = i & 127; nw1T[c * 256 + k] = f2b(nw1[i]); return; }
    i -= 256 * 128;
    if (i < 128 * 128) { int k = i >> 7, c = i & 127; nw2T[c * 128 + k] = f2b(nw2[i]); }
}

// ---------------------------------------------------------------------------
// Edge kernel, software-pipelined one tile deep:
//   iter: [issue gathers(t+1)] L1(t) -> barrier(lds) -> ds_write x(t+1),
//         L2(t), epilogue(t) (stores+atomics NOT drained) -> barrier(lds)
// LDS: XOR-swizzled (byte ^= (row&7)<<4), no pads.
//   xs row = 512B (256 bf16), ys row = 256B (128 bf16).
// Staging map: e = lane, seg = wave (phase-uniform LDS writes, coalesced eidx).
// ---------------------------------------------------------------------------
__global__ __launch_bounds__(256, 2) void edge_kernel(
    const ushort_t* __restrict__ hb, const int* __restrict__ eidx,
    const ushort_t* __restrict__ w1, const float* __restrict__ eb1,
    const ushort_t* __restrict__ w2, const float* __restrict__ eb2,
    float* __restrict__ mij, float* __restrict__ agg) {
    __shared__ __align__(16) ushort_t xs[64 * 256];
    __shared__ __align__(16) ushort_t ys[64 * 128];
    __shared__ int ridx[2][64];

    const int tid = threadIdx.x;
    const int wave = tid >> 6;
    const int lane = tid & 63;
    const int quad = lane >> 4;
    const int ln = lane & 15;
    const int ncol0 = wave * 32;

    // B fragments from transposed weights: contiguous b128 loads.
    short8 b1f[8][2];  // K=256 -> 8 k-steps; 2 column tiles of 16
    short8 b2f[4][2];  // K=128 -> 4 k-steps
#pragma unroll
    for (int kk = 0; kk < 8; kk++)
#pragma unroll
        for (int t = 0; t < 2; t++)
            b1f[kk][t] = *(const short8*)(w1 + (ncol0 + t * 16 + ln) * 256 + kk * 32 + quad * 8);
#pragma unroll
    for (int kk = 0; kk < 4; kk++)
#pragma unroll
        for (int t = 0; t < 2; t++)
            b2f[kk][t] = *(const short8*)(w2 + (ncol0 + t * 16 + ln) * 128 + kk * 32 + quad * 8);
    const float bv1[2] = {eb1[ncol0 + ln], eb1[ncol0 + 16 + ln]};
    const float bv2[2] = {eb2[ncol0 + ln], eb2[ncol0 + 16 + ln]};

    const int NT = E / 64;
    const int e = lane;    // staged edge slot
    const int seg = wave;  // quarter of the x row
    char* const xrow = (char*)xs + e * 512;
    const int xswz = (e & 7) << 4;

    int tile = blockIdx.x;

    // ---- prologue: stage tile 0 ----
    {
        const int r = eidx[tile * 64 + e];
        const int c = eidx[E + tile * 64 + e];
        if (seg == 0) ridx[0][e] = r;
        const int node = (seg < 2) ? r : c;
        const uint4* src = (const uint4*)(hb + node * 128 + (seg & 1) * 64);
#pragma unroll
        for (int u = 0; u < 8; u++)
            *(uint4*)(xrow + ((seg * 128 + u * 16) ^ xswz)) = src[u];
    }
    wg_barrier_lds();

    int p = 0;
    for (; tile < NT; tile += gridDim.x) {
        const int e0 = tile * 64;
        int tn = tile + gridDim.x;
        if (tn >= NT) tn = tile;  // last iter: restage same tile (unused)

        // ---- issue next-tile gathers early (consumed after mid barrier) ----
        const int rn = eidx[tn * 64 + e];
        const int cn = eidx[E + tn * 64 + e];
        const int noden = (seg < 2) ? rn : cn;
        const uint4* srcn = (const uint4*)(hb + noden * 128 + (seg & 1) * 64);
        uint4 st[8];
#pragma unroll
        for (int u = 0; u < 8; u++) st[u] = srcn[u];

        // ---- layer 1 ----
        f32x4 acc[4][2];
#pragma unroll
        for (int mt = 0; mt < 4; mt++)
#pragma unroll
            for (int t = 0; t < 2; t++) acc[mt][t] = f32x4{bv1[t], bv1[t], bv1[t], bv1[t]};
#pragma unroll
        for (int kk = 0; kk < 8; kk++)
#pragma unroll
            for (int mt = 0; mt < 4; mt++) {
                const int row = mt * 16 + ln;
                short8 a = *(const short8*)((char*)xs + row * 512 +
                                            ((kk * 64 + quad * 16) ^ ((ln & 7) << 4)));
                acc[mt][0] = MFMA16(a, b1f[kk][0], acc[mt][0]);
                acc[mt][1] = MFMA16(a, b1f[kk][1], acc[mt][1]);
            }
        // silu -> packed bf16 pair -> ys (C/D layout: row = quad*4 + r, col = ln)
#pragma unroll
        for (int mt = 0; mt < 4; mt++)
#pragma unroll
            for (int r4 = 0; r4 < 4; r4++) {
                const int row = mt * 16 + quad * 4 + r4;
                const uint_t pk = cvt_pk_bf16(silu(acc[mt][0][r4]), silu(acc[mt][1][r4]));
                char* yrow = (char*)ys + row * 256;
                const int ysw = (row & 7) << 4;
                const int cb = 2 * (ncol0 + ln);
                *(ushort_t*)(yrow + (cb ^ ysw)) = (ushort_t)pk;
                *(ushort_t*)(yrow + ((cb + 32) ^ ysw)) = (ushort_t)(pk >> 16);
            }
        wg_barrier_lds();  // ys ready; all waves done reading xs

        // ---- stage next x tile (writes wait only on own gathers) ----
        if (seg == 0) ridx[p ^ 1][e] = rn;
#pragma unroll
        for (int u = 0; u < 8; u++)
            *(uint4*)(xrow + ((seg * 128 + u * 16) ^ xswz)) = st[u];

        // ---- layer 2 ----
        f32x4 acc2[4][2];
#pragma unroll
        for (int mt = 0; mt < 4; mt++)
#pragma unroll
            for (int t = 0; t < 2; t++) acc2[mt][t] = f32x4{bv2[t], bv2[t], bv2[t], bv2[t]};
#pragma unroll
        for (int kk = 0; kk < 4; kk++)
#pragma unroll
            for (int mt = 0; mt < 4; mt++) {
                const int row = mt * 16 + ln;
                short8 a = *(const short8*)((char*)ys + row * 256 +
                                            ((kk * 64 + quad * 16) ^ ((ln & 7) << 4)));
                acc2[mt][0] = MFMA16(a, b2f[kk][0], acc2[mt][0]);
                acc2[mt][1] = MFMA16(a, b2f[kk][1], acc2[mt][1]);
            }

        // ---- epilogue: silu, store mij, scatter-add agg (no drain) ----
#pragma unroll
        for (int mt = 0; mt < 4; mt++)
#pragma unroll
            for (int r4 = 0; r4 < 4; r4++) {
                const int row = mt * 16 + quad * 4 + r4;
                const int nsrc = ridx[p][row];
#pragma unroll
                for (int t = 0; t < 2; t++) {
                    const float s = silu(acc2[mt][t][r4]);
                    const int col = ncol0 + t * 16 + ln;
                    mij[(size_t)(e0 + row) * 128 + col] = s;
                    unsafeAtomicAdd(&agg[nsrc * 128 + col], s);
                }
            }
        wg_barrier_lds();  // LDS-only: epilogue stores/atomics keep flying
        p ^= 1;
    }
}

// ---------------------------------------------------------------------------
// Node kernel: a = concat(h, agg/100); out = h + silu(a @ NW1 + nb1) @ NW2 + nb2
// Same swizzled LDS + transposed-weight fragments. One 64-row tile per block.
// ---------------------------------------------------------------------------
__global__ __launch_bounds__(256, 2) void node_kernel(
    const ushort_t* __restrict__ hb, const float* __restrict__ h32,
    const float* __restrict__ agg,
    const ushort_t* __restrict__ w1, const float* __restrict__ nb1,
    const ushort_t* __restrict__ w2, const float* __restrict__ nb2,
    float* __restrict__ out) {
    __shared__ __align__(16) ushort_t xs[64 * 256];
    __shared__ __align__(16) ushort_t ys[64 * 128];

    const int tid = threadIdx.x;
    const int wave = tid >> 6;
    const int lane = tid & 63;
    const int quad = lane >> 4;
    const int ln = lane & 15;
    const int ncol0 = wave * 32;
    const int i0 = blockIdx.x * 64;

    short8 b1f[8][2];
    short8 b2f[4][2];
#pragma unroll
    for (int kk = 0; kk < 8; kk++)
#pragma unroll
        for (int t = 0; t < 2; t++)
            b1f[kk][t] = *(const short8*)(w1 + (ncol0 + t * 16 + ln) * 256 + kk * 32 + quad * 8);
#pragma unroll
    for (int kk = 0; kk < 4; kk++)
#pragma unroll
        for (int t = 0; t < 2; t++)
            b2f[kk][t] = *(const short8*)(w2 + (ncol0 + t * 16 + ln) * 128 + kk * 32 + quad * 8);
    const float bv1[2] = {nb1[ncol0 + ln], nb1[ncol0 + 16 + ln]};
    const float bv2[2] = {nb2[ncol0 + ln], nb2[ncol0 + 16 + ln]};

    const int e = lane, seg = wave;
    char* const xrow = (char*)xs + e * 512;
    const int xswz = (e & 7) << 4;
    const int node = i0 + e;

    // ---- stage: segs 0,1 = h (bf16 copy); segs 2,3 = agg * (1/100) ----
    if (node < V) {
        if (seg < 2) {
            const uint4* src = (const uint4*)(hb + node * 128 + seg * 64);
#pragma unroll
            for (int u = 0; u < 8; u++)
                *(uint4*)(xrow + ((seg * 128 + u * 16) ^ xswz)) = src[u];
        } else {
            const float4* src = (const float4*)(agg + node * 128 + (seg & 1) * 64);
#pragma unroll
            for (int u = 0; u < 8; u++) {
                float4 a = src[2 * u], b = src[2 * u + 1];
                uint4 v;
                v.x = cvt_pk_bf16(a.x * 0.01f, a.y * 0.01f);
                v.y = cvt_pk_bf16(a.z * 0.01f, a.w * 0.01f);
                v.z = cvt_pk_bf16(b.x * 0.01f, b.y * 0.01f);
                v.w = cvt_pk_bf16(b.z * 0.01f, b.w * 0.01f);
                *(uint4*)(xrow + ((seg * 128 + u * 16) ^ xswz)) = v;
            }
        }
    } else {
        const uint4 z{0, 0, 0, 0};
#pragma unroll
        for (int u = 0; u < 8; u++)
            *(uint4*)(xrow + ((seg * 128 + u * 16) ^ xswz)) = z;
    }
    __syncthreads();

    // ---- layer 1 (silu) ----
    f32x4 acc[4][2];
#pragma unroll
    for (int mt = 0; mt < 4; mt++)
#pragma unroll
        for (int t = 0; t < 2; t++) acc[mt][t] = f32x4{bv1[t], bv1[t], bv1[t], bv1[t]};
#pragma unroll
    for (int kk = 0; kk < 8; kk++)
#pragma unroll
        for (int mt = 0; mt < 4; mt++) {
            const int row = mt * 16 + ln;
            short8 a = *(const short8*)((char*)xs + row * 512 +
                                        ((kk * 64 + quad * 16) ^ ((ln & 7) << 4)));
            acc[mt][0] = MFMA16(a, b1f[kk][0], acc[mt][0]);
            acc[mt][1] = MFMA16(a, b1f[kk][1], acc[mt][1]);
        }
#pragma unroll
    for (int mt = 0; mt < 4; mt++)
#pragma unroll
        for (int r4 = 0; r4 < 4; r4++) {
            const int row = mt * 16 + quad * 4 + r4;
            const uint_t pk = cvt_pk_bf16(silu(acc[mt][0][r4]), silu(acc[mt][1][r4]));
            char* yrow = (char*)ys + row * 256;
            const int ysw = (row & 7) << 4;
            const int cb = 2 * (ncol0 + ln);
            *(ushort_t*)(yrow + (cb ^ ysw)) = (ushort_t)pk;
            *(ushort_t*)(yrow + ((cb + 32) ^ ysw)) = (ushort_t)(pk >> 16);
        }
    __syncthreads();

    // ---- layer 2 (no activation) + residual ----
    f32x4 acc2[4][2];
#pragma unroll
    for (int mt = 0; mt < 4; mt++)
#pragma unroll
        for (int t = 0; t < 2; t++) acc2[mt][t] = f32x4{bv2[t], bv2[t], bv2[t], bv2[t]};
#pragma unroll
    for (int kk = 0; kk < 4; kk++)
#pragma unroll
        for (int mt = 0; mt < 4; mt++) {
            const int row = mt * 16 + ln;
            short8 a = *(const short8*)((char*)ys + row * 256 +
                                        ((kk * 64 + quad * 16) ^ ((ln & 7) << 4)));
            acc2[mt][0] = MFMA16(a, b2f[kk][0], acc2[mt][0]);
            acc2[mt][1] = MFMA16(a, b2f[kk][1], acc2[mt][1]);
        }
#pragma unroll
    for (int mt = 0; mt < 4; mt++)
#pragma unroll
        for (int r4 = 0; r4 < 4; r4++) {
            const int row = mt * 16 + quad * 4 + r4;
            const int nd = i0 + row;
            if (nd < V) {
#pragma unroll
                for (int t = 0; t < 2; t++) {
                    const int col = ncol0 + t * 16 + ln;
                    out[(size_t)nd * 128 + col] = h32[(size_t)nd * 128 + col] + acc2[mt][t][r4];
                }
            }
        }
}

extern "C" void kernel_launch(void* const* d_in, const int* in_sizes, int n_in,
                              void* d_out, int out_size, void* d_ws, size_t ws_size,
                              hipStream_t stream) {
    const float* h = (const float*)d_in[0];
    const int* eidx = (const int*)d_in[1];
    const float* ew1 = (const float*)d_in[2];
    const float* eb1 = (const float*)d_in[3];
    const float* ew2 = (const float*)d_in[4];
    const float* eb2 = (const float*)d_in[5];
    const float* nw1 = (const float*)d_in[6];
    const float* nb1 = (const float*)d_in[7];
    const float* nw2 = (const float*)d_in[8];
    const float* nb2 = (const float*)d_in[9];

    float* out = (float*)d_out;                    // [V,128]
    float* mij = (float*)d_out + (size_t)V * 128;  // [E,128]

    // workspace layout (unchanged offsets; w matrices now stored TRANSPOSED)
    uint8_t* ws = (uint8_t*)d_ws;
    ushort_t* hb = (ushort_t*)(ws);                       // 2,560,000 B
    ushort_t* w1b = (ushort_t*)(ws + 2560000);            // 65,536 B  [128][256]
    ushort_t* w2b = (ushort_t*)(ws + 2560000 + 65536);    // 32,768 B  [128][128]
    ushort_t* nw1b = (ushort_t*)(ws + 2560000 + 98304);   // 65,536 B  [128][256]
    ushort_t* nw2b = (ushort_t*)(ws + 2560000 + 163840);  // 32,768 B  [128][128]
    float* agg = (float*)(ws + 2560000 + 196608);         // 5,120,000 B

    // one fused prep dispatch: h->bf16, agg=0, 4x weight convert+transpose
    constexpr int PREP_N = V * 128 + V * 128 + 256 * 128 + 128 * 128 + 256 * 128 + 128 * 128;
    prep<<<(PREP_N + 255) / 256, 256, 0, stream>>>(h, ew1, ew2, nw1, nw2,
                                                   hb, w1b, w2b, nw1b, nw2b, agg);

    edge_kernel<<<2000, 256, 0, stream>>>(hb, eidx, w1b, eb1, w2b, eb2, mij, agg);
    node_kernel<<<(V + 63) / 64, 256, 0, stream>>>(hb, h, agg, nw1b, nb1, nw2b, nb2, out);
}

// Round 3
// 602.371 us; speedup vs baseline: 1.0036x; 1.0036x over previous
//
#include <hip/hip_runtime.h>

typedef __attribute__((ext_vector_type(8))) short short8;
typedef __attribute__((ext_vector_type(4))) float f32x4;
typedef unsigned short ushort_t;
typedef unsigned int uint_t;

#define MFMA16(a, b, c) __builtin_amdgcn_mfma_f32_16x16x32_bf16((a), (b), (c), 0, 0, 0)

constexpr int V = 10000;
constexpr int E = 640000;

__device__ __forceinline__ ushort_t f2b(float f) {
    uint_t u = __float_as_uint(f);
    u += 0x7FFFu + ((u >> 16) & 1u);
    return (ushort_t)(u >> 16);
}

__device__ __forceinline__ float silu(float x) {
    return x / (1.0f + __expf(-x));
}

__device__ __forceinline__ uint_t cvt_pk_bf16(float lo, float hi) {
    uint_t r;
    asm("v_cvt_pk_bf16_f32 %0, %1, %2" : "=v"(r) : "v"(lo), "v"(hi));
    return r;
}

// LDS-only workgroup barrier: does not drain vmcnt.
__device__ __forceinline__ void wg_barrier_lds() {
    asm volatile("s_waitcnt lgkmcnt(0)" ::: "memory");
    __builtin_amdgcn_s_barrier();
    asm volatile("" ::: "memory");
}

// ---------------------------------------------------------------------------
// prep: h->bf16, agg=0, cnt=0, 4x weight convert+TRANSPOSE (wT[c*K+k]).
// ---------------------------------------------------------------------------
__global__ void prep(const float* __restrict__ h,
                     const float* __restrict__ ew1, const float* __restrict__ ew2,
                     const float* __restrict__ nw1, const float* __restrict__ nw2,
                     ushort_t* __restrict__ hb,
                     ushort_t* __restrict__ w1T, ushort_t* __restrict__ w2T,
                     ushort_t* __restrict__ nw1T, ushort_t* __restrict__ nw2T,
                     float* __restrict__ agg, int* __restrict__ cnt) {
    int i = blockIdx.x * blockDim.x + threadIdx.x;
    if (i < V * 128) { hb[i] = f2b(h[i]); return; }
    i -= V * 128;
    if (i < V * 128) { agg[i] = 0.0f; return; }
    i -= V * 128;
    if (i < 256 * 128) { int k = i >> 7, c = i & 127; w1T[c * 256 + k] = f2b(ew1[i]); return; }
    i -= 256 * 128;
    if (i < 128 * 128) { int k = i >> 7, c = i & 127; w2T[c * 128 + k] = f2b(ew2[i]); return; }
    i -= 128 * 128;
    if (i < 256 * 128) { int k = i >> 7, c = i & 127; nw1T[c * 256 + k] = f2b(nw1[i]); return; }
    i -= 256 * 128;
    if (i < 128 * 128) { int k = i >> 7, c = i & 127; nw2T[c * 128 + k] = f2b(nw2[i]); return; }
    i -= 128 * 128;
    if (i < V) cnt[i] = 0;
}

__global__ void hist_kernel(const int* __restrict__ eidx, int* __restrict__ cnt) {
    int e = blockIdx.x * blockDim.x + threadIdx.x;
    if (e < E) atomicAdd(&cnt[eidx[e]], 1);
}

// Single-block exclusive scan: cursor[i] = sum_{j<i} cnt[j]. cnt is read-only.
__global__ __launch_bounds__(256) void scan_kernel(const int* __restrict__ cnt,
                                                   int* __restrict__ cursor) {
    __shared__ int part[256];
    const int t = threadIdx.x;
    const int base = t * 40;  // 256*40 = 10240 >= V
    int s = 0;
#pragma unroll 1
    for (int i = 0; i < 40; i++) {
        int idx = base + i;
        s += (idx < V) ? cnt[idx] : 0;
    }
    part[t] = s;
    __syncthreads();
    for (int off = 1; off < 256; off <<= 1) {
        int v = (t >= off) ? part[t - off] : 0;
        __syncthreads();
        part[t] += v;
        __syncthreads();
    }
    int run = (t == 0) ? 0 : part[t - 1];
#pragma unroll 1
    for (int i = 0; i < 40; i++) {
        int idx = base + i;
        if (idx < V) {
            cursor[idx] = run;
            run += cnt[idx];
        }
    }
}

__global__ void scatter_kernel(const int* __restrict__ eidx, int* __restrict__ cursor,
                               int* __restrict__ perm) {
    int e = blockIdx.x * blockDim.x + threadIdx.x;
    if (e < E) {
        int pos = atomicAdd(&cursor[eidx[e]], 1);
        perm[pos] = e;
    }
}

// ---------------------------------------------------------------------------
// Edge kernel over row-sorted edges (perm). Tile = 64 edges, ~1-3 row-segments.
// Epilogue: mij scatter-store at original edge id; agg via in-register
// segmented reduction (masked sums + shfl_xor across quads), one f32 atomic
// per segment per column instead of one per edge per column.
// ---------------------------------------------------------------------------
__global__ __launch_bounds__(256, 2) void edge_kernel(
    const ushort_t* __restrict__ hb, const int* __restrict__ eidx,
    const int* __restrict__ perm,
    const ushort_t* __restrict__ w1, const float* __restrict__ eb1,
    const ushort_t* __restrict__ w2, const float* __restrict__ eb2,
    float* __restrict__ mij, float* __restrict__ agg) {
    __shared__ __align__(16) ushort_t xs[64 * 256];
    __shared__ __align__(16) ushort_t ys[64 * 128];
    __shared__ int ridx[2][64];
    __shared__ int pidx[2][64];

    const int tid = threadIdx.x;
    const int wave = tid >> 6;
    const int lane = tid & 63;
    const int quad = lane >> 4;
    const int ln = lane & 15;
    const int ncol0 = wave * 32;
    const int lnswz = (ln & 7) << 4;

    short8 b1f[8][2];
    short8 b2f[4][2];
#pragma unroll
    for (int kk = 0; kk < 8; kk++)
#pragma unroll
        for (int t = 0; t < 2; t++)
            b1f[kk][t] = *(const short8*)(w1 + (ncol0 + t * 16 + ln) * 256 + kk * 32 + quad * 8);
#pragma unroll
    for (int kk = 0; kk < 4; kk++)
#pragma unroll
        for (int t = 0; t < 2; t++)
            b2f[kk][t] = *(const short8*)(w2 + (ncol0 + t * 16 + ln) * 128 + kk * 32 + quad * 8);
    const float bv1[2] = {eb1[ncol0 + ln], eb1[ncol0 + 16 + ln]};
    const float bv2[2] = {eb2[ncol0 + ln], eb2[ncol0 + 16 + ln]};

    const int NT = E / 64;
    const int G = gridDim.x;
    const int e = lane;
    const int seg = wave;
    char* const xrow = (char*)xs + e * 512;
    const int xswz = (e & 7) << 4;

    int tile = blockIdx.x;

    // ---- prologue: indices + stage tile 0 ----
    {
        const int pe = perm[tile * 64 + e];
        const int r = eidx[pe];
        const int c = eidx[E + pe];
        if (seg == 0) { ridx[0][e] = r; pidx[0][e] = pe; }
        const int node = (seg < 2) ? r : c;
        const uint4* src = (const uint4*)(hb + node * 128 + (seg & 1) * 64);
#pragma unroll
        for (int u = 0; u < 8; u++)
            *(uint4*)(xrow + ((seg * 128 + u * 16) ^ xswz)) = src[u];
    }
    // indices for tile+G (one iteration ahead)
    int t1 = tile + G; if (t1 >= NT) t1 = tile;
    int pe1 = perm[t1 * 64 + e];
    int r1 = eidx[pe1];
    int c1 = eidx[E + pe1];
    wg_barrier_lds();

    int p = 0;
    for (; tile < NT; tile += G) {
        // ---- gathers for next tile (indices already resident) ----
        const int noden = (seg < 2) ? r1 : c1;
        const uint4* srcn = (const uint4*)(hb + noden * 128 + (seg & 1) * 64);
        uint4 st[8];
#pragma unroll
        for (int u = 0; u < 8; u++) st[u] = srcn[u];

        // ---- indices for tile+2G ----
        int t2 = tile + 2 * G; if (t2 >= NT) t2 = tile;
        const int pe2 = perm[t2 * 64 + e];
        const int r2 = eidx[pe2];
        const int c2 = eidx[E + pe2];

        // ---- layer 1 ----
        f32x4 acc[4][2];
#pragma unroll
        for (int mt = 0; mt < 4; mt++)
#pragma unroll
            for (int t = 0; t < 2; t++) acc[mt][t] = f32x4{bv1[t], bv1[t], bv1[t], bv1[t]};
#pragma unroll
        for (int kk = 0; kk < 8; kk++)
#pragma unroll
            for (int mt = 0; mt < 4; mt++) {
                const int row = mt * 16 + ln;
                short8 a = *(const short8*)((char*)xs + row * 512 +
                                            ((kk * 64 + quad * 16) ^ lnswz));
                acc[mt][0] = MFMA16(a, b1f[kk][0], acc[mt][0]);
                acc[mt][1] = MFMA16(a, b1f[kk][1], acc[mt][1]);
            }
#pragma unroll
        for (int mt = 0; mt < 4; mt++)
#pragma unroll
            for (int r4 = 0; r4 < 4; r4++) {
                const int row = mt * 16 + quad * 4 + r4;
                const uint_t pk = cvt_pk_bf16(silu(acc[mt][0][r4]), silu(acc[mt][1][r4]));
                char* yrow = (char*)ys + row * 256;
                const int ysw = (row & 7) << 4;
                const int cb = 2 * (ncol0 + ln);
                *(ushort_t*)(yrow + (cb ^ ysw)) = (ushort_t)pk;
                *(ushort_t*)(yrow + ((cb + 32) ^ ysw)) = (ushort_t)(pk >> 16);
            }
        wg_barrier_lds();

        // ---- stage next x tile ----
        if (seg == 0) { ridx[p ^ 1][e] = r1; pidx[p ^ 1][e] = pe1; }
#pragma unroll
        for (int u = 0; u < 8; u++)
            *(uint4*)(xrow + ((seg * 128 + u * 16) ^ xswz)) = st[u];

        // ---- layer 2 ----
        f32x4 acc2[4][2];
#pragma unroll
        for (int mt = 0; mt < 4; mt++)
#pragma unroll
            for (int t = 0; t < 2; t++) acc2[mt][t] = f32x4{bv2[t], bv2[t], bv2[t], bv2[t]};
#pragma unroll
        for (int kk = 0; kk < 4; kk++)
#pragma unroll
            for (int mt = 0; mt < 4; mt++) {
                const int row = mt * 16 + ln;
                short8 a = *(const short8*)((char*)ys + row * 256 +
                                            ((kk * 64 + quad * 16) ^ lnswz));
                acc2[mt][0] = MFMA16(a, b2f[kk][0], acc2[mt][0]);
                acc2[mt][1] = MFMA16(a, b2f[kk][1], acc2[mt][1]);
            }

        // ---- epilogue: silu in place, scatter-store mij at original edge id ----
#pragma unroll
        for (int mt = 0; mt < 4; mt++)
#pragma unroll
            for (int r4 = 0; r4 < 4; r4++) {
                const int row = mt * 16 + quad * 4 + r4;
                const int pe = pidx[p][row];
#pragma unroll
                for (int t = 0; t < 2; t++) {
                    const float s = silu(acc2[mt][t][r4]);
                    acc2[mt][t][r4] = s;
                    mij[(size_t)pe * 128 + ncol0 + t * 16 + ln] = s;
                }
            }

        // ---- segmented in-register reduction -> few agg atomics ----
        {
            const int myn = ridx[p][lane];
            const int prevn = (lane == 0) ? (myn + 1) : ridx[p][lane - 1];
            unsigned long long bmask = __ballot(lane == 0 || myn != prevn);
            while (bmask) {
                const int a = __builtin_ctzll(bmask);
                bmask &= bmask - 1;
                const int b = bmask ? __builtin_ctzll(bmask) : 64;
                float s0 = 0.0f, s1 = 0.0f;
#pragma unroll
                for (int mt = 0; mt < 4; mt++)
#pragma unroll
                    for (int r4 = 0; r4 < 4; r4++) {
                        const int row = mt * 16 + quad * 4 + r4;
                        const bool in = (row >= a) && (row < b);
                        s0 += in ? acc2[mt][0][r4] : 0.0f;
                        s1 += in ? acc2[mt][1][r4] : 0.0f;
                    }
                s0 += __shfl_xor(s0, 16);
                s0 += __shfl_xor(s0, 32);
                s1 += __shfl_xor(s1, 16);
                s1 += __shfl_xor(s1, 32);
                if (quad == 0) {
                    const int node = ridx[p][a];
                    unsafeAtomicAdd(&agg[node * 128 + ncol0 + ln], s0);
                    unsafeAtomicAdd(&agg[node * 128 + ncol0 + 16 + ln], s1);
                }
            }
        }
        wg_barrier_lds();
        pe1 = pe2; r1 = r2; c1 = c2;
        p ^= 1;
    }
}

// ---------------------------------------------------------------------------
// Node kernel: a = concat(h, agg/100); out = h + silu(a @ NW1 + nb1) @ NW2 + nb2
// ---------------------------------------------------------------------------
__global__ __launch_bounds__(256, 2) void node_kernel(
    const ushort_t* __restrict__ hb, const float* __restrict__ h32,
    const float* __restrict__ agg,
    const ushort_t* __restrict__ w1, const float* __restrict__ nb1,
    const ushort_t* __restrict__ w2, const float* __restrict__ nb2,
    float* __restrict__ out) {
    __shared__ __align__(16) ushort_t xs[64 * 256];
    __shared__ __align__(16) ushort_t ys[64 * 128];

    const int tid = threadIdx.x;
    const int wave = tid >> 6;
    const int lane = tid & 63;
    const int quad = lane >> 4;
    const int ln = lane & 15;
    const int ncol0 = wave * 32;
    const int i0 = blockIdx.x * 64;
    const int lnswz = (ln & 7) << 4;

    short8 b1f[8][2];
    short8 b2f[4][2];
#pragma unroll
    for (int kk = 0; kk < 8; kk++)
#pragma unroll
        for (int t = 0; t < 2; t++)
            b1f[kk][t] = *(const short8*)(w1 + (ncol0 + t * 16 + ln) * 256 + kk * 32 + quad * 8);
#pragma unroll
    for (int kk = 0; kk < 4; kk++)
#pragma unroll
        for (int t = 0; t < 2; t++)
            b2f[kk][t] = *(const short8*)(w2 + (ncol0 + t * 16 + ln) * 128 + kk * 32 + quad * 8);
    const float bv1[2] = {nb1[ncol0 + ln], nb1[ncol0 + 16 + ln]};
    const float bv2[2] = {nb2[ncol0 + ln], nb2[ncol0 + 16 + ln]};

    const int e = lane, seg = wave;
    char* const xrow = (char*)xs + e * 512;
    const int xswz = (e & 7) << 4;
    const int node = i0 + e;

    if (node < V) {
        if (seg < 2) {
            const uint4* src = (const uint4*)(hb + node * 128 + seg * 64);
#pragma unroll
            for (int u = 0; u < 8; u++)
                *(uint4*)(xrow + ((seg * 128 + u * 16) ^ xswz)) = src[u];
        } else {
            const float4* src = (const float4*)(agg + node * 128 + (seg & 1) * 64);
#pragma unroll
            for (int u = 0; u < 8; u++) {
                float4 a = src[2 * u], b = src[2 * u + 1];
                uint4 v;
                v.x = cvt_pk_bf16(a.x * 0.01f, a.y * 0.01f);
                v.y = cvt_pk_bf16(a.z * 0.01f, a.w * 0.01f);
                v.z = cvt_pk_bf16(b.x * 0.01f, b.y * 0.01f);
                v.w = cvt_pk_bf16(b.z * 0.01f, b.w * 0.01f);
                *(uint4*)(xrow + ((seg * 128 + u * 16) ^ xswz)) = v;
            }
        }
    } else {
        const uint4 z{0, 0, 0, 0};
#pragma unroll
        for (int u = 0; u < 8; u++)
            *(uint4*)(xrow + ((seg * 128 + u * 16) ^ xswz)) = z;
    }
    __syncthreads();

    f32x4 acc[4][2];
#pragma unroll
    for (int mt = 0; mt < 4; mt++)
#pragma unroll
        for (int t = 0; t < 2; t++) acc[mt][t] = f32x4{bv1[t], bv1[t], bv1[t], bv1[t]};
#pragma unroll
    for (int kk = 0; kk < 8; kk++)
#pragma unroll
        for (int mt = 0; mt < 4; mt++) {
            const int row = mt * 16 + ln;
            short8 a = *(const short8*)((char*)xs + row * 512 +
                                        ((kk * 64 + quad * 16) ^ lnswz));
            acc[mt][0] = MFMA16(a, b1f[kk][0], acc[mt][0]);
            acc[mt][1] = MFMA16(a, b1f[kk][1], acc[mt][1]);
        }
#pragma unroll
    for (int mt = 0; mt < 4; mt++)
#pragma unroll
        for (int r4 = 0; r4 < 4; r4++) {
            const int row = mt * 16 + quad * 4 + r4;
            const uint_t pk = cvt_pk_bf16(silu(acc[mt][0][r4]), silu(acc[mt][1][r4]));
            char* yrow = (char*)ys + row * 256;
            const int ysw = (row & 7) << 4;
            const int cb = 2 * (ncol0 + ln);
            *(ushort_t*)(yrow + (cb ^ ysw)) = (ushort_t)pk;
            *(ushort_t*)(yrow + ((cb + 32) ^ ysw)) = (ushort_t)(pk >> 16);
        }
    __syncthreads();

    f32x4 acc2[4][2];
#pragma unroll
    for (int mt = 0; mt < 4; mt++)
#pragma unroll
        for (int t = 0; t < 2; t++) acc2[mt][t] = f32x4{bv2[t], bv2[t], bv2[t], bv2[t]};
#pragma unroll
    for (int kk = 0; kk < 4; kk++)
#pragma unroll
        for (int mt = 0; mt < 4; mt++) {
            const int row = mt * 16 + ln;
            short8 a = *(const short8*)((char*)ys + row * 256 +
                                        ((kk * 64 + quad * 16) ^ lnswz));
            acc2[mt][0] = MFMA16(a, b2f[kk][0], acc2[mt][0]);
            acc2[mt][1] = MFMA16(a, b2f[kk][1], acc2[mt][1]);
        }
#pragma unroll
    for (int mt = 0; mt < 4; mt++)
#pragma unroll
        for (int r4 = 0; r4 < 4; r4++) {
            const int row = mt * 16 + quad * 4 + r4;
            const int nd = i0 + row;
            if (nd < V) {
#pragma unroll
                for (int t = 0; t < 2; t++) {
                    const int col = ncol0 + t * 16 + ln;
                    out[(size_t)nd * 128 + col] = h32[(size_t)nd * 128 + col] + acc2[mt][t][r4];
                }
            }
        }
}

extern "C" void kernel_launch(void* const* d_in, const int* in_sizes, int n_in,
                              void* d_out, int out_size, void* d_ws, size_t ws_size,
                              hipStream_t stream) {
    const float* h = (const float*)d_in[0];
    const int* eidx = (const int*)d_in[1];
    const float* ew1 = (const float*)d_in[2];
    const float* eb1 = (const float*)d_in[3];
    const float* ew2 = (const float*)d_in[4];
    const float* eb2 = (const float*)d_in[5];
    const float* nw1 = (const float*)d_in[6];
    const float* nb1 = (const float*)d_in[7];
    const float* nw2 = (const float*)d_in[8];
    const float* nb2 = (const float*)d_in[9];

    float* out = (float*)d_out;                    // [V,128]
    float* mij = (float*)d_out + (size_t)V * 128;  // [E,128]

    // workspace layout
    uint8_t* ws = (uint8_t*)d_ws;
    ushort_t* hb = (ushort_t*)(ws);                       // 2,560,000 B
    ushort_t* w1b = (ushort_t*)(ws + 2560000);            // 65,536 B  [128][256]
    ushort_t* w2b = (ushort_t*)(ws + 2560000 + 65536);    // 32,768 B  [128][128]
    ushort_t* nw1b = (ushort_t*)(ws + 2560000 + 98304);   // 65,536 B  [128][256]
    ushort_t* nw2b = (ushort_t*)(ws + 2560000 + 163840);  // 32,768 B  [128][128]
    float* agg = (float*)(ws + 2756608);                  // 5,120,000 B
    int* cnt = (int*)(ws + 7876608);                      // 40,000 B
    int* perm = (int*)(ws + 7916608);                     // 2,560,000 B
    int* cursor = (int*)(ws + 10476608);                  // 40,000 B

    constexpr int PREP_N =
        V * 128 + V * 128 + 256 * 128 + 128 * 128 + 256 * 128 + 128 * 128 + V;
    prep<<<(PREP_N + 255) / 256, 256, 0, stream>>>(h, ew1, ew2, nw1, nw2,
                                                   hb, w1b, w2b, nw1b, nw2b, agg, cnt);
    hist_kernel<<<(E + 255) / 256, 256, 0, stream>>>(eidx, cnt);
    scan_kernel<<<1, 256, 0, stream>>>(cnt, cursor);
    scatter_kernel<<<(E + 255) / 256, 256, 0, stream>>>(eidx, cursor, perm);

    edge_kernel<<<2000, 256, 0, stream>>>(hb, eidx, perm, w1b, eb1, w2b, eb2, mij, agg);
    node_kernel<<<(V + 63) / 64, 256, 0, stream>>>(hb, h, agg, nw1b, nb1, nw2b, nb2, out);
}